// Round 1
// baseline (2924.383 us; speedup 1.0000x reference)
//
#include <hip/hip_runtime.h>
#include <hip/hip_bf16.h>

#define NPIX   65536
#define TT     5
#define CC     10
#define HH     32
#define WIDTH  64
#define KW     32
#define OUTC   10

// ---- workspace layout (float offsets) ----
// LSTM weights k-major gate-packed for streaming: [k][j][g], g=(i,f,g,o)
#define OFF_L0I    0        // 1280  [c][j][g]
#define OFF_L0H    1280     // 4096  [k][j][g]
#define OFF_L1I    5376     // 4096
#define OFF_L1H    9472     // 4096
#define OFF_B0     13568    // 128   [j][g]
#define OFF_B1     13696    // 128
#define OFF_FC1W   13824    // 2048  [k][ch]
#define OFF_FC1B   15872    // 64
#define OFF_CWT2   16384    // 16384 [k][co2][ci] float2 (conv, LDS-staged)
#define OFF_CB     32768    // 256
#define OFF_FC2W2  33024    // 2048  [m2][ch] float2
#define OFF_FC2B   35072    // 32
#define OFF_FC3W4  35104    // 320   [oc2][m2] float4
#define OFF_FC3B   35424    // 16
#define OFF_GW     35440    // 8
#define OFF_FEATS_A 36864
#define OFF_FEATS_B (36864 + 8388608)

#define STRAIGHT_ATTR_IDX (65025 * 3)

typedef float v2f __attribute__((ext_vector_type(2)));

__device__ __forceinline__ float sigf(float x)  { return 1.0f / (1.0f + __expf(-x)); }
__device__ __forceinline__ float tanhf_(float x){ return 1.0f - 2.0f / (__expf(2.0f * x) + 1.0f); }

// ---------------- prep: pack params ----------------
__global__ __launch_bounds__(256, 1)
void prep_kernel(const float* Wih0, const float* Whh0,
                 const float* bih0, const float* bhh0,
                 const float* Wih1, const float* Whh1,
                 const float* bih1, const float* bhh1,
                 const float* fc1w, const float* fc1b,
                 const float* convw, const float* convb,
                 const float* fc2w, const float* fc2b,
                 const float* fc3w, const float* fc3b,
                 const float* gparam, const float* eattr,
                 float* P) {
    int tid = blockIdx.x * blockDim.x + threadIdx.x;
    int stride = gridDim.x * blockDim.x;
    // LSTM k-major: [k][j][g] <- W[(g*32+j)*K + k]
    for (int idx = tid; idx < 1280; idx += stride) {
        int g = idx & 3, j = (idx >> 2) & 31, c = idx >> 7;
        P[OFF_L0I + idx] = Wih0[(g * 32 + j) * 10 + c];
    }
    for (int idx = tid; idx < 4096; idx += stride) {
        int g = idx & 3, j = (idx >> 2) & 31, k = idx >> 7;
        P[OFF_L0H + idx] = Whh0[(g * 32 + j) * 32 + k];
        P[OFF_L1I + idx] = Wih1[(g * 32 + j) * 32 + k];
        P[OFF_L1H + idx] = Whh1[(g * 32 + j) * 32 + k];
    }
    for (int idx = tid; idx < 128; idx += stride) {
        int g = idx & 3, j = idx >> 2;
        P[OFF_B0 + idx] = bih0[g * 32 + j] + bhh0[g * 32 + j];
        P[OFF_B1 + idx] = bih1[g * 32 + j] + bhh1[g * 32 + j];
    }
    // fc1 k-major [k][ch]
    for (int idx = tid; idx < 2048; idx += stride) {
        int ch = idx & 63, k = idx >> 6;
        P[OFF_FC1W + idx] = fc1w[ch * 32 + k];
    }
    for (int i = tid; i < 64; i += stride) P[OFF_FC1B + i] = fc1b[i];
    // conv [k][co2][ci] float2
    for (int idx = tid; idx < 16384; idx += stride) {
        int k = idx >> 12, r = idx & 4095, e = r >> 1, h = r & 1;
        int co2 = e >> 6, ci = e & 63;
        P[OFF_CWT2 + idx] = convw[k * 4096 + ci * 64 + (2 * co2 + h)];
    }
    for (int i = tid; i < 256; i += stride) P[OFF_CB + i] = convb[i];
    for (int idx = tid; idx < 2048; idx += stride) {
        int e = idx >> 1, h = idx & 1, m2 = e >> 6, ch = e & 63;
        P[OFF_FC2W2 + idx] = fc2w[(2 * m2 + h) * 64 + ch];
    }
    for (int i = tid; i < 32;  i += stride) P[OFF_FC2B + i] = fc2b[i];
    for (int idx = tid; idx < 320; idx += stride) {
        int q = idx & 3, e = idx >> 2, oc2 = e >> 4, m2 = e & 15;
        int oc = 2 * oc2 + (q & 1), m = 2 * m2 + (q >> 1);
        P[OFF_FC3W4 + idx] = fc3w[oc * 32 + m];
    }
    for (int i = tid; i < 10; i += stride) P[OFF_FC3B + i] = fc3b[i];
    for (int idx = tid; idx < 8; idx += stride) {
        int k = idx >> 1;
        float g = gparam[k];
        float denom = g * g + 1e-8f;
        float a = (idx & 1) ? eattr[0] : eattr[STRAIGHT_ATTR_IDX];
        P[OFF_GW + idx] = __expf(-(a * a) / denom);
    }
}

// ---------------- LSTM: lane-pair j-split, packed-fp32 accumulators ----------------
// 256 thr/block, 128 px/block: lanes 2i,2i+1 share pixel i; half=tid&1 owns
// hidden units j in [half*16, half*16+16). z shrinks to 32 v2f (64 VGPR) so all
// accumulators stay in arch VGPRs (no AGPR ping-pong). Both halves of a pixel
// sit in the SAME wave -> lockstep makes read-old-h / write-new-h safe with no
// barriers. 4096 waves total -> 4 waves/SIMD (launch_bounds caps VGPR at 128).
// Gate pairs go through float2 ext-vectors -> v_pk_fma_f32 (2 FMA/inst).
__device__ __forceinline__ void mv_row(const float* __restrict__ wr, float s,
                                       v2f zA[16], v2f zB[16]) {
    v2f s2 = {s, s};
    const float4* w4 = (const float4*)wr;
#pragma unroll
    for (int j = 0; j < 16; j++) {
        float4 q = w4[j];
        v2f wa = {q.x, q.y};
        v2f wb = {q.z, q.w};
        zA[j] = __builtin_elementwise_fma(wa, s2, zA[j]);
        zB[j] = __builtin_elementwise_fma(wb, s2, zB[j]);
    }
}

__device__ __forceinline__ float gate_update(v2f a, v2f g, float& c) {
    // a = (i,f), g = (g,o)
    float cn = sigf(a.y) * c + sigf(a.x) * tanhf_(g.x);
    c = cn;
    return sigf(g.y) * tanhf_(cn);
}

__global__ __launch_bounds__(256, 4)
void lstm_fc1_kernel(const float* __restrict__ x,
                     const float* __restrict__ P,
                     float* __restrict__ feats) {
    __shared__ float H0[HH * 128];   // 16384 B  [j][pxl]
    __shared__ float H1[HH * 128];   // 16384 B  (total 32768)

    int tid  = threadIdx.x;
    int half = tid & 1;           // which 16 hidden units this lane owns
    int pxl  = tid >> 1;          // pixel column within block (0..127)
    int hw   = half << 4;         // j offset: 0 or 16
    int n = blockIdx.x * 128 + pxl;
    int b = n >> 16;
    int pix = n & (NPIX - 1);
    const float* xb = x + (size_t)b * TT * CC * NPIX + pix;

    float c0[16], c1[16];
#pragma unroll
    for (int j = 0; j < 16; j++) {
        c0[j] = 0.f; c1[j] = 0.f;
        H0[(hw + j) * 128 + pxl] = 0.f;
        H1[(hw + j) * 128 + pxl] = 0.f;
    }

#pragma unroll 1
    for (int t = 0; t < TT; t++) {
        float xcur[CC];
#pragma unroll
        for (int c = 0; c < CC; c++)
            xcur[c] = xb[(size_t)(t * CC + c) * NPIX];

        // ---- layer 0 ----
        {
            v2f zA[16], zB[16];
            const float4* bb = ((const float4*)(P + OFF_B0)) + hw;
#pragma unroll
            for (int j = 0; j < 16; j++) {
                float4 q = bb[j];
                zA[j] = v2f{q.x, q.y}; zB[j] = v2f{q.z, q.w};
            }
#pragma unroll
            for (int c = 0; c < CC; c++)
                mv_row(P + OFF_L0I + c * 128 + (half << 6), xcur[c], zA, zB);
#pragma unroll 1
            for (int k = 0; k < HH; k++) {
                float hv = H0[k * 128 + pxl];
                mv_row(P + OFF_L0H + k * 128 + (half << 6), hv, zA, zB);
            }
            // all H0-old reads above are complete (lockstep wave) -> safe to write
#pragma unroll
            for (int j = 0; j < 16; j++)
                H0[(hw + j) * 128 + pxl] = gate_update(zA[j], zB[j], c0[j]);
        }

        // ---- layer 1 ----
        {
            v2f zA[16], zB[16];
            const float4* bb = ((const float4*)(P + OFF_B1)) + hw;
#pragma unroll
            for (int j = 0; j < 16; j++) {
                float4 q = bb[j];
                zA[j] = v2f{q.x, q.y}; zB[j] = v2f{q.z, q.w};
            }
#pragma unroll 1
            for (int k = 0; k < HH; k++) {
                float hv = H0[k * 128 + pxl];          // h0(t), fully written
                mv_row(P + OFF_L1I + k * 128 + (half << 6), hv, zA, zB);
            }
#pragma unroll 1
            for (int k = 0; k < HH; k++) {
                float hv = H1[k * 128 + pxl];          // h1(t-1)
                mv_row(P + OFF_L1H + k * 128 + (half << 6), hv, zA, zB);
            }
#pragma unroll
            for (int j = 0; j < 16; j++)
                H1[(hw + j) * 128 + pxl] = gate_update(zA[j], zB[j], c1[j]);
        }
    }

    // ---- fc1 + relu: half picks 32 of the 64 output channels ----
    v2f fv[16];
    {
        const float4* bb = ((const float4*)(P + OFF_FC1B)) + (half << 3);
#pragma unroll
        for (int m = 0; m < 8; m++) {
            float4 q = bb[m];
            fv[2 * m]     = v2f{q.x, q.y};
            fv[2 * m + 1] = v2f{q.z, q.w};
        }
    }
#pragma unroll 1
    for (int k = 0; k < HH; k++) {
        float hv = H1[k * 128 + pxl];
        v2f h2 = {hv, hv};
        const float4* wr = (const float4*)(P + OFF_FC1W + k * 64 + (half << 5));
#pragma unroll
        for (int m = 0; m < 8; m++) {
            float4 q = wr[m];
            v2f wa = {q.x, q.y};
            v2f wb = {q.z, q.w};
            fv[2 * m]     = __builtin_elementwise_fma(wa, h2, fv[2 * m]);
            fv[2 * m + 1] = __builtin_elementwise_fma(wb, h2, fv[2 * m + 1]);
        }
    }
    float* fb = feats + (size_t)b * WIDTH * NPIX + (size_t)(half * 32) * NPIX + pix;
#pragma unroll
    for (int m = 0; m < 16; m++) {
        fb[(size_t)(2 * m) * NPIX]     = fmaxf(fv[m].x, 0.f);
        fb[(size_t)(2 * m + 1) * NPIX] = fmaxf(fv[m].y, 0.f);
    }
}

// ---------------- fused conv layer (unchanged: 256 thr, 1 px/lane) ----------------
__global__ __launch_bounds__(256, 1)
void conv_fused_kernel(const float* __restrict__ Fin, float* __restrict__ Fout,
                       const float* __restrict__ P, int k) {
    __shared__ float4 CW[1024];   // [co2][ci2]
    __shared__ float  CB[64];
    {
        const float4* src = (const float4*)(P + OFF_CWT2 + k * 4096);
        for (int i = threadIdx.x; i < 1024; i += 256) CW[i] = src[i];
        if (threadIdx.x < 64) CB[threadIdx.x] = P[OFF_CB + k * 64 + threadIdx.x];
    }
    __syncthreads();

    int n = blockIdx.x * 256 + threadIdx.x;
    int b = n >> 16;
    int pix = n & (NPIX - 1);
    int i = pix >> 8, j = pix & 255;
    float wstr = P[OFF_GW + 2 * k], wdiag = P[OFF_GW + 2 * k + 1];
    float fu = (i > 0) ? wstr : 0.f, fd = (i < 255) ? wstr : 0.f;
    float fl = (j > 0) ? wstr : 0.f, fr = (j < 255) ? wstr : 0.f;
    float ful = (i > 0 && j > 0) ? wdiag : 0.f, fur = (i > 0 && j < 255) ? wdiag : 0.f;
    float fdl = (i < 255 && j > 0) ? wdiag : 0.f, fdr = (i < 255 && j < 255) ? wdiag : 0.f;

    const float* fb = Fin + (size_t)b * WIDTH * NPIX + pix;
    float u[WIDTH];
#pragma unroll
    for (int ch = 0; ch < WIDTH; ch++) {
        const float* yc = fb + (size_t)ch * NPIX;
        float v = yc[0];
        v += fu * yc[-256] + fd * yc[256] + fl * yc[-1] + fr * yc[1];
        v += ful * yc[-257] + fur * yc[-255] + fdl * yc[255] + fdr * yc[257];
        u[ch] = v;
    }

    float* ob = Fout + (size_t)b * WIDTH * NPIX + pix;
#pragma unroll 1
    for (int co2 = 0; co2 < 32; co2++) {
        float ax = CB[2 * co2], ay = CB[2 * co2 + 1];
        const float4* wv = CW + co2 * 32;
#pragma unroll
        for (int ci2 = 0; ci2 < 32; ci2++) {
            float4 q = wv[ci2];
            float a0 = u[2 * ci2], a1 = u[2 * ci2 + 1];
            ax = __builtin_fmaf(q.x, a0, ax); ax = __builtin_fmaf(q.z, a1, ax);
            ay = __builtin_fmaf(q.y, a0, ay); ay = __builtin_fmaf(q.w, a1, ay);
        }
        ob[(size_t)(2 * co2) * NPIX]     = fmaxf(ax, 0.f);
        ob[(size_t)(2 * co2 + 1) * NPIX] = fmaxf(ay, 0.f);
    }
}

// ---------------- last conv (no relu) + fc2/fc3 head (unchanged) ----------------
__global__ __launch_bounds__(256, 1)
void conv_head_kernel(const float* __restrict__ Fin, const float* __restrict__ P,
                      float* __restrict__ out) {
    const int k = 3;
    __shared__ float4 CW3[1024];
    __shared__ float  CB3[64];
    __shared__ float4 F2W[512];
    __shared__ float  F2B[32];
    __shared__ float4 F3W[80];
    __shared__ float  F3B[12];
    {
        const float4* s1 = (const float4*)(P + OFF_CWT2 + k * 4096);
        for (int i = threadIdx.x; i < 1024; i += 256) CW3[i] = s1[i];
        const float4* s2 = (const float4*)(P + OFF_FC2W2);
        for (int i = threadIdx.x; i < 512; i += 256) F2W[i] = s2[i];
        const float4* s3 = (const float4*)(P + OFF_FC3W4);
        if (threadIdx.x < 80) F3W[threadIdx.x] = s3[threadIdx.x];
        if (threadIdx.x < 64) CB3[threadIdx.x] = P[OFF_CB + k * 64 + threadIdx.x];
        if (threadIdx.x < 32) F2B[threadIdx.x] = P[OFF_FC2B + threadIdx.x];
        if (threadIdx.x < 10) F3B[threadIdx.x] = P[OFF_FC3B + threadIdx.x];
    }
    __syncthreads();

    int n = blockIdx.x * 256 + threadIdx.x;
    int b = n >> 16;
    int pix = n & (NPIX - 1);
    int i = pix >> 8, j = pix & 255;
    float wstr = P[OFF_GW + 2 * k], wdiag = P[OFF_GW + 2 * k + 1];
    float fu = (i > 0) ? wstr : 0.f, fd = (i < 255) ? wstr : 0.f;
    float fl = (j > 0) ? wstr : 0.f, fr = (j < 255) ? wstr : 0.f;
    float ful = (i > 0 && j > 0) ? wdiag : 0.f, fur = (i > 0 && j < 255) ? wdiag : 0.f;
    float fdl = (i < 255 && j > 0) ? wdiag : 0.f, fdr = (i < 255 && j < 255) ? wdiag : 0.f;

    const float* fb = Fin + (size_t)b * WIDTH * NPIX + pix;
    float u[WIDTH];
#pragma unroll
    for (int ch = 0; ch < WIDTH; ch++) {
        const float* yc = fb + (size_t)ch * NPIX;
        float v = yc[0];
        v += fu * yc[-256] + fd * yc[256] + fl * yc[-1] + fr * yc[1];
        v += ful * yc[-257] + fur * yc[-255] + fdl * yc[255] + fdr * yc[257];
        u[ch] = v;
    }

    float f[WIDTH];
#pragma unroll
    for (int co2 = 0; co2 < 32; co2++) {
        float ax = CB3[2 * co2], ay = CB3[2 * co2 + 1];
        const float4* wv = CW3 + co2 * 32;
#pragma unroll
        for (int ci2 = 0; ci2 < 32; ci2++) {
            float4 q = wv[ci2];
            float a0 = u[2 * ci2], a1 = u[2 * ci2 + 1];
            ax = __builtin_fmaf(q.x, a0, ax); ax = __builtin_fmaf(q.z, a1, ax);
            ay = __builtin_fmaf(q.y, a0, ay); ay = __builtin_fmaf(q.w, a1, ay);
        }
        f[2 * co2] = ax; f[2 * co2 + 1] = ay;
    }

    float2 oo[5];
#pragma unroll
    for (int oc2 = 0; oc2 < 5; oc2++) oo[oc2] = make_float2(F3B[2 * oc2], F3B[2 * oc2 + 1]);
#pragma unroll 1
    for (int m2 = 0; m2 < 16; m2++) {
        float ax = F2B[2 * m2], ay = F2B[2 * m2 + 1];
        const float4* wv = F2W + m2 * 32;
#pragma unroll
        for (int ch2 = 0; ch2 < 32; ch2++) {
            float4 q = wv[ch2];
            ax = __builtin_fmaf(q.x, f[2 * ch2], ax); ax = __builtin_fmaf(q.z, f[2 * ch2 + 1], ax);
            ay = __builtin_fmaf(q.y, f[2 * ch2], ay); ay = __builtin_fmaf(q.w, f[2 * ch2 + 1], ay);
        }
        ax = fmaxf(ax, 0.f); ay = fmaxf(ay, 0.f);
#pragma unroll
        for (int oc2 = 0; oc2 < 5; oc2++) {
            float4 q = F3W[oc2 * 16 + m2];
            oo[oc2].x += q.x * ax + q.z * ay;
            oo[oc2].y += q.y * ax + q.w * ay;
        }
    }
    float* ob = out + (size_t)b * OUTC * NPIX + pix;
#pragma unroll
    for (int oc2 = 0; oc2 < 5; oc2++) {
        ob[(size_t)(2 * oc2) * NPIX]     = oo[oc2].x;
        ob[(size_t)(2 * oc2 + 1) * NPIX] = oo[oc2].y;
    }
}

extern "C" void kernel_launch(void* const* d_in, const int* in_sizes, int n_in,
                              void* d_out, int out_size, void* d_ws, size_t ws_size,
                              hipStream_t stream) {
    const float* x     = (const float*)d_in[0];
    const float* eattr = (const float*)d_in[3];
    const float* Wih0  = (const float*)d_in[4];
    const float* Whh0  = (const float*)d_in[5];
    const float* bih0  = (const float*)d_in[6];
    const float* bhh0  = (const float*)d_in[7];
    const float* Wih1  = (const float*)d_in[8];
    const float* Whh1  = (const float*)d_in[9];
    const float* bih1  = (const float*)d_in[10];
    const float* bhh1  = (const float*)d_in[11];
    const float* fc1w  = (const float*)d_in[12];
    const float* fc1b  = (const float*)d_in[13];
    const float* convw = (const float*)d_in[14];
    const float* convb = (const float*)d_in[15];
    const float* gparam= (const float*)d_in[16];
    const float* fc2w  = (const float*)d_in[17];
    const float* fc2b  = (const float*)d_in[18];
    const float* fc3w  = (const float*)d_in[19];
    const float* fc3b  = (const float*)d_in[20];

    float* P  = (float*)d_ws;
    float* FA = P + OFF_FEATS_A;
    float* FB = P + OFF_FEATS_B;

    prep_kernel<<<64, 256, 0, stream>>>(Wih0, Whh0, bih0, bhh0, Wih1, Whh1, bih1, bhh1,
                                        fc1w, fc1b, convw, convb, fc2w, fc2b, fc3w, fc3b,
                                        gparam, eattr, P);
    lstm_fc1_kernel<<<1024, 256, 0, stream>>>(x, P, FA);
    conv_fused_kernel<<<512, 256, 0, stream>>>(FA, FB, P, 0);
    conv_fused_kernel<<<512, 256, 0, stream>>>(FB, FA, P, 1);
    conv_fused_kernel<<<512, 256, 0, stream>>>(FA, FB, P, 2);
    conv_head_kernel<<<512, 256, 0, stream>>>(FB, P, (float*)d_out);
}

// Round 2
// 857.286 us; speedup vs baseline: 3.4112x; 3.4112x over previous
//
#include <hip/hip_runtime.h>
#include <hip/hip_bf16.h>

#define NPIX   65536
#define TT     5
#define CC     10
#define HH     32
#define WIDTH  64
#define KW     32
#define OUTC   10

// ---- workspace layout (float offsets) ----
// LSTM weights k-major gate-packed for SGPR streaming: [k][j][g], g=(i,f,g,o)
#define OFF_L0I    0        // 1280  [c][j][g]
#define OFF_L0H    1280     // 4096  [k][j][g]
#define OFF_L1I    5376     // 4096
#define OFF_L1H    9472     // 4096
#define OFF_B0     13568    // 128   [j][g]
#define OFF_B1     13696    // 128
#define OFF_FC1W   13824    // 2048  [k][ch]
#define OFF_FC1B   15872    // 64
#define OFF_CWT2   16384    // 16384 [k][co2][ci] float2 (conv, LDS-staged)
#define OFF_CB     32768    // 256
#define OFF_FC2W2  33024    // 2048  [m2][ch] float2
#define OFF_FC2B   35072    // 32
#define OFF_FC3W4  35104    // 320   [oc2][m2] float4
#define OFF_FC3B   35424    // 16
#define OFF_GW     35440    // 8
#define OFF_FEATS_A 36864
#define OFF_FEATS_B (36864 + 8388608)

#define STRAIGHT_ATTR_IDX (65025 * 3)

__device__ __forceinline__ float sigf(float x)  { return 1.0f / (1.0f + __expf(-x)); }
__device__ __forceinline__ float tanhf_(float x){ return 1.0f - 2.0f / (__expf(2.0f * x) + 1.0f); }

// ---------------- prep: pack params ----------------
__global__ __launch_bounds__(256, 1)
void prep_kernel(const float* Wih0, const float* Whh0,
                 const float* bih0, const float* bhh0,
                 const float* Wih1, const float* Whh1,
                 const float* bih1, const float* bhh1,
                 const float* fc1w, const float* fc1b,
                 const float* convw, const float* convb,
                 const float* fc2w, const float* fc2b,
                 const float* fc3w, const float* fc3b,
                 const float* gparam, const float* eattr,
                 float* P) {
    int tid = blockIdx.x * blockDim.x + threadIdx.x;
    int stride = gridDim.x * blockDim.x;
    // LSTM k-major: [k][j][g] <- W[(g*32+j)*K + k]
    for (int idx = tid; idx < 1280; idx += stride) {
        int g = idx & 3, j = (idx >> 2) & 31, c = idx >> 7;
        P[OFF_L0I + idx] = Wih0[(g * 32 + j) * 10 + c];
    }
    for (int idx = tid; idx < 4096; idx += stride) {
        int g = idx & 3, j = (idx >> 2) & 31, k = idx >> 7;
        P[OFF_L0H + idx] = Whh0[(g * 32 + j) * 32 + k];
        P[OFF_L1I + idx] = Wih1[(g * 32 + j) * 32 + k];
        P[OFF_L1H + idx] = Whh1[(g * 32 + j) * 32 + k];
    }
    for (int idx = tid; idx < 128; idx += stride) {
        int g = idx & 3, j = idx >> 2;
        P[OFF_B0 + idx] = bih0[g * 32 + j] + bhh0[g * 32 + j];
        P[OFF_B1 + idx] = bih1[g * 32 + j] + bhh1[g * 32 + j];
    }
    // fc1 k-major [k][ch]
    for (int idx = tid; idx < 2048; idx += stride) {
        int ch = idx & 63, k = idx >> 6;
        P[OFF_FC1W + idx] = fc1w[ch * 32 + k];
    }
    for (int i = tid; i < 64; i += stride) P[OFF_FC1B + i] = fc1b[i];
    // conv [k][co2][ci] float2
    for (int idx = tid; idx < 16384; idx += stride) {
        int k = idx >> 12, r = idx & 4095, e = r >> 1, h = r & 1;
        int co2 = e >> 6, ci = e & 63;
        P[OFF_CWT2 + idx] = convw[k * 4096 + ci * 64 + (2 * co2 + h)];
    }
    for (int i = tid; i < 256; i += stride) P[OFF_CB + i] = convb[i];
    for (int idx = tid; idx < 2048; idx += stride) {
        int e = idx >> 1, h = idx & 1, m2 = e >> 6, ch = e & 63;
        P[OFF_FC2W2 + idx] = fc2w[(2 * m2 + h) * 64 + ch];
    }
    for (int i = tid; i < 32;  i += stride) P[OFF_FC2B + i] = fc2b[i];
    for (int idx = tid; idx < 320; idx += stride) {
        int q = idx & 3, e = idx >> 2, oc2 = e >> 4, m2 = e & 15;
        int oc = 2 * oc2 + (q & 1), m = 2 * m2 + (q >> 1);
        P[OFF_FC3W4 + idx] = fc3w[oc * 32 + m];
    }
    for (int i = tid; i < 10; i += stride) P[OFF_FC3B + i] = fc3b[i];
    for (int idx = tid; idx < 8; idx += stride) {
        int k = idx >> 1;
        float g = gparam[k];
        float denom = g * g + 1e-8f;
        float a = (idx & 1) ? eattr[0] : eattr[STRAIGHT_ATTR_IDX];
        P[OFF_GW + idx] = __expf(-(a * a) / denom);
    }
}

// ---------------- LSTM: wave-level j-split, SGPR weight streaming ----------------
// 256 thr/block = 4 waves, 128 px/block. Waves 0-1 (tid<128) own hidden units
// j in [0,16); waves 2-3 own j in [16,32). half = readfirstlane(tid>>7) is an
// SGPR, so every weight address stays WAVE-UNIFORM -> s_load into SGPRs (zero
// VGPR cost; round-1's per-lane weight loads caused the spill disaster).
// Per-lane state: z 64 + c 32 + x 10 ~= 118 VGPR, fits the (256,4) cap of 128.
// h state in LDS [j][pxl]; halves live in different waves -> 4 barriers per t.
#define ROW_ACC(WBASE, SVAL) do {                                   \
    const float* wr_ = (WBASE); float sv_ = (SVAL);                 \
    _Pragma("unroll")                                               \
    for (int j_ = 0; j_ < 16; j_++) {                               \
        z[j_].x = __builtin_fmaf(wr_[4 * j_ + 0], sv_, z[j_].x);    \
        z[j_].y = __builtin_fmaf(wr_[4 * j_ + 1], sv_, z[j_].y);    \
        z[j_].z = __builtin_fmaf(wr_[4 * j_ + 2], sv_, z[j_].z);    \
        z[j_].w = __builtin_fmaf(wr_[4 * j_ + 3], sv_, z[j_].w);    \
    } } while (0)

__global__ __launch_bounds__(256, 4)
void lstm_fc1_kernel(const float* __restrict__ x,
                     const float* __restrict__ P,
                     float* __restrict__ feats) {
    __shared__ float H0[HH * 128];   // 16384 B  [j][pxl]
    __shared__ float H1[HH * 128];   // 16384 B  (total 32768)

    int tid  = threadIdx.x;
    // wave-uniform by construction; readfirstlane pins it to an SGPR so the
    // compiler provably keeps all weight addresses scalar (s_load).
    int half = __builtin_amdgcn_readfirstlane(tid >> 7);
    int pxl  = tid & 127;            // pixel column within block (0..127)
    int hw   = half << 4;            // j offset: 0 or 16
    int hw4  = half << 6;            // float offset into 128-wide gate rows

    int n = blockIdx.x * 128 + pxl;
    int b = n >> 16;
    int pix = n & (NPIX - 1);
    const float* xb = x + (size_t)b * TT * CC * NPIX + pix;

    float c0[16], c1[16];
#pragma unroll
    for (int j = 0; j < 16; j++) {
        c0[j] = 0.f; c1[j] = 0.f;
        H0[(hw + j) * 128 + pxl] = 0.f;
        H1[(hw + j) * 128 + pxl] = 0.f;
    }
    __syncthreads();

#pragma unroll 1
    for (int t = 0; t < TT; t++) {
        float xcur[CC];
#pragma unroll
        for (int c = 0; c < CC; c++)
            xcur[c] = xb[(size_t)(t * CC + c) * NPIX];

        // ---- layer 0 ----
        {
            float4 z[16];
            const float* bb = P + OFF_B0 + hw4;
#pragma unroll
            for (int j = 0; j < 16; j++)
                z[j] = *(const float4*)(bb + 4 * j);
#pragma unroll
            for (int c = 0; c < CC; c++)
                ROW_ACC(P + OFF_L0I + c * 128 + hw4, xcur[c]);
#pragma unroll 1
            for (int k = 0; k < HH; k++) {
                float hv = H0[k * 128 + pxl];     // h0(t-1)
                ROW_ACC(P + OFF_L0H + k * 128 + hw4, hv);
            }
            __syncthreads();                      // all waves done reading old H0
#pragma unroll
            for (int j = 0; j < 16; j++) {
                float cn = sigf(z[j].y) * c0[j] + sigf(z[j].x) * tanhf_(z[j].z);
                c0[j] = cn;
                H0[(hw + j) * 128 + pxl] = sigf(z[j].w) * tanhf_(cn);
            }
            __syncthreads();                      // new H0 visible
        }

        // ---- layer 1 ----
        {
            float4 z[16];
            const float* bb = P + OFF_B1 + hw4;
#pragma unroll
            for (int j = 0; j < 16; j++)
                z[j] = *(const float4*)(bb + 4 * j);
#pragma unroll 1
            for (int k = 0; k < HH; k++) {
                float hv = H0[k * 128 + pxl];     // h0(t)
                ROW_ACC(P + OFF_L1I + k * 128 + hw4, hv);
            }
#pragma unroll 1
            for (int k = 0; k < HH; k++) {
                float hv = H1[k * 128 + pxl];     // h1(t-1)
                ROW_ACC(P + OFF_L1H + k * 128 + hw4, hv);
            }
            __syncthreads();                      // all waves done reading old H1
#pragma unroll
            for (int j = 0; j < 16; j++) {
                float cn = sigf(z[j].y) * c1[j] + sigf(z[j].x) * tanhf_(z[j].z);
                c1[j] = cn;
                H1[(hw + j) * 128 + pxl] = sigf(z[j].w) * tanhf_(cn);
            }
            __syncthreads();                      // new H1 visible
        }
    }

    // ---- fc1 + relu: half picks 32 of the 64 output channels ----
    float f[32];
    {
        const float* fb1 = P + OFF_FC1B + (half << 5);
#pragma unroll
        for (int m = 0; m < 32; m++) f[m] = fb1[m];
    }
#pragma unroll 1
    for (int k = 0; k < HH; k++) {
        float hv = H1[k * 128 + pxl];
        const float* wr = P + OFF_FC1W + k * 64 + (half << 5);
#pragma unroll
        for (int m = 0; m < 32; m++)
            f[m] = __builtin_fmaf(wr[m], hv, f[m]);
    }
    float* fob = feats + (size_t)b * WIDTH * NPIX + (size_t)(half * 32) * NPIX + pix;
#pragma unroll
    for (int m = 0; m < 32; m++)
        fob[(size_t)m * NPIX] = fmaxf(f[m], 0.f);
}

// ---------------- fused conv layer (unchanged: 256 thr, 1 px/lane) ----------------
__global__ __launch_bounds__(256, 1)
void conv_fused_kernel(const float* __restrict__ Fin, float* __restrict__ Fout,
                       const float* __restrict__ P, int k) {
    __shared__ float4 CW[1024];   // [co2][ci2]
    __shared__ float  CB[64];
    {
        const float4* src = (const float4*)(P + OFF_CWT2 + k * 4096);
        for (int i = threadIdx.x; i < 1024; i += 256) CW[i] = src[i];
        if (threadIdx.x < 64) CB[threadIdx.x] = P[OFF_CB + k * 64 + threadIdx.x];
    }
    __syncthreads();

    int n = blockIdx.x * 256 + threadIdx.x;
    int b = n >> 16;
    int pix = n & (NPIX - 1);
    int i = pix >> 8, j = pix & 255;
    float wstr = P[OFF_GW + 2 * k], wdiag = P[OFF_GW + 2 * k + 1];
    float fu = (i > 0) ? wstr : 0.f, fd = (i < 255) ? wstr : 0.f;
    float fl = (j > 0) ? wstr : 0.f, fr = (j < 255) ? wstr : 0.f;
    float ful = (i > 0 && j > 0) ? wdiag : 0.f, fur = (i > 0 && j < 255) ? wdiag : 0.f;
    float fdl = (i < 255 && j > 0) ? wdiag : 0.f, fdr = (i < 255 && j < 255) ? wdiag : 0.f;

    const float* fb = Fin + (size_t)b * WIDTH * NPIX + pix;
    float u[WIDTH];
#pragma unroll
    for (int ch = 0; ch < WIDTH; ch++) {
        const float* yc = fb + (size_t)ch * NPIX;
        float v = yc[0];
        v += fu * yc[-256] + fd * yc[256] + fl * yc[-1] + fr * yc[1];
        v += ful * yc[-257] + fur * yc[-255] + fdl * yc[255] + fdr * yc[257];
        u[ch] = v;
    }

    float* ob = Fout + (size_t)b * WIDTH * NPIX + pix;
#pragma unroll 1
    for (int co2 = 0; co2 < 32; co2++) {
        float ax = CB[2 * co2], ay = CB[2 * co2 + 1];
        const float4* wv = CW + co2 * 32;
#pragma unroll
        for (int ci2 = 0; ci2 < 32; ci2++) {
            float4 q = wv[ci2];
            float a0 = u[2 * ci2], a1 = u[2 * ci2 + 1];
            ax = __builtin_fmaf(q.x, a0, ax); ax = __builtin_fmaf(q.z, a1, ax);
            ay = __builtin_fmaf(q.y, a0, ay); ay = __builtin_fmaf(q.w, a1, ay);
        }
        ob[(size_t)(2 * co2) * NPIX]     = fmaxf(ax, 0.f);
        ob[(size_t)(2 * co2 + 1) * NPIX] = fmaxf(ay, 0.f);
    }
}

// ---------------- last conv (no relu) + fc2/fc3 head (unchanged) ----------------
__global__ __launch_bounds__(256, 1)
void conv_head_kernel(const float* __restrict__ Fin, const float* __restrict__ P,
                      float* __restrict__ out) {
    const int k = 3;
    __shared__ float4 CW3[1024];
    __shared__ float  CB3[64];
    __shared__ float4 F2W[512];
    __shared__ float  F2B[32];
    __shared__ float4 F3W[80];
    __shared__ float  F3B[12];
    {
        const float4* s1 = (const float4*)(P + OFF_CWT2 + k * 4096);
        for (int i = threadIdx.x; i < 1024; i += 256) CW3[i] = s1[i];
        const float4* s2 = (const float4*)(P + OFF_FC2W2);
        for (int i = threadIdx.x; i < 512; i += 256) F2W[i] = s2[i];
        const float4* s3 = (const float4*)(P + OFF_FC3W4);
        if (threadIdx.x < 80) F3W[threadIdx.x] = s3[threadIdx.x];
        if (threadIdx.x < 64) CB3[threadIdx.x] = P[OFF_CB + k * 64 + threadIdx.x];
        if (threadIdx.x < 32) F2B[threadIdx.x] = P[OFF_FC2B + threadIdx.x];
        if (threadIdx.x < 10) F3B[threadIdx.x] = P[OFF_FC3B + threadIdx.x];
    }
    __syncthreads();

    int n = blockIdx.x * 256 + threadIdx.x;
    int b = n >> 16;
    int pix = n & (NPIX - 1);
    int i = pix >> 8, j = pix & 255;
    float wstr = P[OFF_GW + 2 * k], wdiag = P[OFF_GW + 2 * k + 1];
    float fu = (i > 0) ? wstr : 0.f, fd = (i < 255) ? wstr : 0.f;
    float fl = (j > 0) ? wstr : 0.f, fr = (j < 255) ? wstr : 0.f;
    float ful = (i > 0 && j > 0) ? wdiag : 0.f, fur = (i > 0 && j < 255) ? wdiag : 0.f;
    float fdl = (i < 255 && j > 0) ? wdiag : 0.f, fdr = (i < 255 && j < 255) ? wdiag : 0.f;

    const float* fb = Fin + (size_t)b * WIDTH * NPIX + pix;
    float u[WIDTH];
#pragma unroll
    for (int ch = 0; ch < WIDTH; ch++) {
        const float* yc = fb + (size_t)ch * NPIX;
        float v = yc[0];
        v += fu * yc[-256] + fd * yc[256] + fl * yc[-1] + fr * yc[1];
        v += ful * yc[-257] + fur * yc[-255] + fdl * yc[255] + fdr * yc[257];
        u[ch] = v;
    }

    float f[WIDTH];
#pragma unroll
    for (int co2 = 0; co2 < 32; co2++) {
        float ax = CB3[2 * co2], ay = CB3[2 * co2 + 1];
        const float4* wv = CW3 + co2 * 32;
#pragma unroll
        for (int ci2 = 0; ci2 < 32; ci2++) {
            float4 q = wv[ci2];
            float a0 = u[2 * ci2], a1 = u[2 * ci2 + 1];
            ax = __builtin_fmaf(q.x, a0, ax); ax = __builtin_fmaf(q.z, a1, ax);
            ay = __builtin_fmaf(q.y, a0, ay); ay = __builtin_fmaf(q.w, a1, ay);
        }
        f[2 * co2] = ax; f[2 * co2 + 1] = ay;
    }

    float2 oo[5];
#pragma unroll
    for (int oc2 = 0; oc2 < 5; oc2++) oo[oc2] = make_float2(F3B[2 * oc2], F3B[2 * oc2 + 1]);
#pragma unroll 1
    for (int m2 = 0; m2 < 16; m2++) {
        float ax = F2B[2 * m2], ay = F2B[2 * m2 + 1];
        const float4* wv = F2W + m2 * 32;
#pragma unroll
        for (int ch2 = 0; ch2 < 32; ch2++) {
            float4 q = wv[ch2];
            ax = __builtin_fmaf(q.x, f[2 * ch2], ax); ax = __builtin_fmaf(q.z, f[2 * ch2 + 1], ax);
            ay = __builtin_fmaf(q.y, f[2 * ch2], ay); ay = __builtin_fmaf(q.w, f[2 * ch2 + 1], ay);
        }
        ax = fmaxf(ax, 0.f); ay = fmaxf(ay, 0.f);
#pragma unroll
        for (int oc2 = 0; oc2 < 5; oc2++) {
            float4 q = F3W[oc2 * 16 + m2];
            oo[oc2].x += q.x * ax + q.z * ay;
            oo[oc2].y += q.y * ax + q.w * ay;
        }
    }
    float* ob = out + (size_t)b * OUTC * NPIX + pix;
#pragma unroll
    for (int oc2 = 0; oc2 < 5; oc2++) {
        ob[(size_t)(2 * oc2) * NPIX]     = oo[oc2].x;
        ob[(size_t)(2 * oc2 + 1) * NPIX] = oo[oc2].y;
    }
}

extern "C" void kernel_launch(void* const* d_in, const int* in_sizes, int n_in,
                              void* d_out, int out_size, void* d_ws, size_t ws_size,
                              hipStream_t stream) {
    const float* x     = (const float*)d_in[0];
    const float* eattr = (const float*)d_in[3];
    const float* Wih0  = (const float*)d_in[4];
    const float* Whh0  = (const float*)d_in[5];
    const float* bih0  = (const float*)d_in[6];
    const float* bhh0  = (const float*)d_in[7];
    const float* Wih1  = (const float*)d_in[8];
    const float* Whh1  = (const float*)d_in[9];
    const float* bih1  = (const float*)d_in[10];
    const float* bhh1  = (const float*)d_in[11];
    const float* fc1w  = (const float*)d_in[12];
    const float* fc1b  = (const float*)d_in[13];
    const float* convw = (const float*)d_in[14];
    const float* convb = (const float*)d_in[15];
    const float* gparam= (const float*)d_in[16];
    const float* fc2w  = (const float*)d_in[17];
    const float* fc2b  = (const float*)d_in[18];
    const float* fc3w  = (const float*)d_in[19];
    const float* fc3b  = (const float*)d_in[20];

    float* P  = (float*)d_ws;
    float* FA = P + OFF_FEATS_A;
    float* FB = P + OFF_FEATS_B;

    prep_kernel<<<64, 256, 0, stream>>>(Wih0, Whh0, bih0, bhh0, Wih1, Whh1, bih1, bhh1,
                                        fc1w, fc1b, convw, convb, fc2w, fc2b, fc3w, fc3b,
                                        gparam, eattr, P);
    lstm_fc1_kernel<<<1024, 256, 0, stream>>>(x, P, FA);
    conv_fused_kernel<<<512, 256, 0, stream>>>(FA, FB, P, 0);
    conv_fused_kernel<<<512, 256, 0, stream>>>(FB, FA, P, 1);
    conv_fused_kernel<<<512, 256, 0, stream>>>(FA, FB, P, 2);
    conv_head_kernel<<<512, 256, 0, stream>>>(FB, P, (float*)d_out);
}

// Round 3
// 654.464 us; speedup vs baseline: 4.4684x; 1.3099x over previous
//
#include <hip/hip_runtime.h>
#include <hip/hip_bf16.h>

#define NPIX   65536
#define TT     5
#define CC     10
#define HH     32
#define WIDTH  64
#define KW     32
#define OUTC   10

// ---- workspace layout (float offsets) ----
// LSTM weights k-major gate-packed for SGPR streaming: [k][j][g], g=(i,f,g,o)
#define OFF_L0I    0        // 1280  [c][j][g]
#define OFF_L0H    1280     // 4096  [k][j][g]
#define OFF_L1I    5376     // 4096
#define OFF_L1H    9472     // 4096
#define OFF_B0     13568    // 128   [j][g]
#define OFF_B1     13696    // 128
#define OFF_FC1W   13824    // 2048  [k][ch]
#define OFF_FC1B   15872    // 64
#define OFF_CWT2   16384    // 16384 [k][co2][ci] float2 (conv, LDS-staged)
#define OFF_CB     32768    // 256
#define OFF_FC2W2  33024    // 2048  [m2][ch] float2
#define OFF_FC2B   35072    // 32
#define OFF_FC3W4  35104    // 320   [oc2][m2] float4
#define OFF_FC3B   35424    // 16
#define OFF_GW     35440    // 8
#define OFF_FEATS_A 36864
#define OFF_FEATS_B (36864 + 8388608)

#define STRAIGHT_ATTR_IDX (65025 * 3)

__device__ __forceinline__ float sigf(float x)  { return 1.0f / (1.0f + __expf(-x)); }
__device__ __forceinline__ float tanhf_(float x){ return 1.0f - 2.0f / (__expf(2.0f * x) + 1.0f); }

// ---------------- prep: pack params ----------------
__global__ __launch_bounds__(256, 1)
void prep_kernel(const float* Wih0, const float* Whh0,
                 const float* bih0, const float* bhh0,
                 const float* Wih1, const float* Whh1,
                 const float* bih1, const float* bhh1,
                 const float* fc1w, const float* fc1b,
                 const float* convw, const float* convb,
                 const float* fc2w, const float* fc2b,
                 const float* fc3w, const float* fc3b,
                 const float* gparam, const float* eattr,
                 float* P) {
    int tid = blockIdx.x * blockDim.x + threadIdx.x;
    int stride = gridDim.x * blockDim.x;
    // LSTM k-major: [k][j][g] <- W[(g*32+j)*K + k]
    for (int idx = tid; idx < 1280; idx += stride) {
        int g = idx & 3, j = (idx >> 2) & 31, c = idx >> 7;
        P[OFF_L0I + idx] = Wih0[(g * 32 + j) * 10 + c];
    }
    for (int idx = tid; idx < 4096; idx += stride) {
        int g = idx & 3, j = (idx >> 2) & 31, k = idx >> 7;
        P[OFF_L0H + idx] = Whh0[(g * 32 + j) * 32 + k];
        P[OFF_L1I + idx] = Wih1[(g * 32 + j) * 32 + k];
        P[OFF_L1H + idx] = Whh1[(g * 32 + j) * 32 + k];
    }
    for (int idx = tid; idx < 128; idx += stride) {
        int g = idx & 3, j = idx >> 2;
        P[OFF_B0 + idx] = bih0[g * 32 + j] + bhh0[g * 32 + j];
        P[OFF_B1 + idx] = bih1[g * 32 + j] + bhh1[g * 32 + j];
    }
    // fc1 k-major [k][ch]
    for (int idx = tid; idx < 2048; idx += stride) {
        int ch = idx & 63, k = idx >> 6;
        P[OFF_FC1W + idx] = fc1w[ch * 32 + k];
    }
    for (int i = tid; i < 64; i += stride) P[OFF_FC1B + i] = fc1b[i];
    // conv [k][co2][ci] float2
    for (int idx = tid; idx < 16384; idx += stride) {
        int k = idx >> 12, r = idx & 4095, e = r >> 1, h = r & 1;
        int co2 = e >> 6, ci = e & 63;
        P[OFF_CWT2 + idx] = convw[k * 4096 + ci * 64 + (2 * co2 + h)];
    }
    for (int i = tid; i < 256; i += stride) P[OFF_CB + i] = convb[i];
    for (int idx = tid; idx < 2048; idx += stride) {
        int e = idx >> 1, h = idx & 1, m2 = e >> 6, ch = e & 63;
        P[OFF_FC2W2 + idx] = fc2w[(2 * m2 + h) * 64 + ch];
    }
    for (int i = tid; i < 32;  i += stride) P[OFF_FC2B + i] = fc2b[i];
    for (int idx = tid; idx < 320; idx += stride) {
        int q = idx & 3, e = idx >> 2, oc2 = e >> 4, m2 = e & 15;
        int oc = 2 * oc2 + (q & 1), m = 2 * m2 + (q >> 1);
        P[OFF_FC3W4 + idx] = fc3w[oc * 32 + m];
    }
    for (int i = tid; i < 10; i += stride) P[OFF_FC3B + i] = fc3b[i];
    for (int idx = tid; idx < 8; idx += stride) {
        int k = idx >> 1;
        float g = gparam[k];
        float denom = g * g + 1e-8f;
        float a = (idx & 1) ? eattr[0] : eattr[STRAIGHT_ATTR_IDX];
        P[OFF_GW + idx] = __expf(-(a * a) / denom);
    }
}

// ---------------- LSTM: wave-level j-split, SGPR weight streaming ----------------
// 256 thr/block = 4 waves, 128 px/block. Waves 0-1 (tid<128) own hidden units
// j in [0,16); waves 2-3 own j in [16,32). half = readfirstlane(tid>>7) is an
// SGPR, so every weight address stays WAVE-UNIFORM -> s_load into SGPRs.
// NOTE: __launch_bounds__ second arg MUST stay 1 on this toolchain — arg 4
// empirically imposed a 64-VGPR cap (R1/R2: VGPR_Count=64 + 200MB-2GB scratch
// spill traffic). With (256,1) the ~120-VGPR state fits and occupancy lands
// at 3-4 waves/SIMD naturally.
// All weight-row loops are unroll-1 to bound in-flight scalar rows (SGPR
// pressure); h state in LDS [j][pxl]; 4 barriers per timestep.
#define ROW_ACC(WBASE, SVAL) do {                                   \
    const float* wr_ = (WBASE); float sv_ = (SVAL);                 \
    _Pragma("unroll")                                               \
    for (int j_ = 0; j_ < 16; j_++) {                               \
        z[j_].x = __builtin_fmaf(wr_[4 * j_ + 0], sv_, z[j_].x);    \
        z[j_].y = __builtin_fmaf(wr_[4 * j_ + 1], sv_, z[j_].y);    \
        z[j_].z = __builtin_fmaf(wr_[4 * j_ + 2], sv_, z[j_].z);    \
        z[j_].w = __builtin_fmaf(wr_[4 * j_ + 3], sv_, z[j_].w);    \
    } } while (0)

__global__ __launch_bounds__(256, 1)
void lstm_fc1_kernel(const float* __restrict__ x,
                     const float* __restrict__ P,
                     float* __restrict__ feats) {
    __shared__ float H0[HH * 128];   // 16384 B  [j][pxl]
    __shared__ float H1[HH * 128];   // 16384 B  (total 32768)

    int tid  = threadIdx.x;
    // wave-uniform by construction; readfirstlane pins it to an SGPR so the
    // compiler provably keeps all weight addresses scalar (s_load).
    int half = __builtin_amdgcn_readfirstlane(tid >> 7);
    int pxl  = tid & 127;            // pixel column within block (0..127)
    int hw   = half << 4;            // j offset: 0 or 16
    int hw4  = half << 6;            // float offset into 128-wide gate rows

    int n = blockIdx.x * 128 + pxl;
    int b = n >> 16;
    int pix = n & (NPIX - 1);
    const float* xb = x + (size_t)b * TT * CC * NPIX + pix;

    float c0[16], c1[16];
#pragma unroll
    for (int j = 0; j < 16; j++) {
        c0[j] = 0.f; c1[j] = 0.f;
        H0[(hw + j) * 128 + pxl] = 0.f;
        H1[(hw + j) * 128 + pxl] = 0.f;
    }
    __syncthreads();

#pragma unroll 1
    for (int t = 0; t < TT; t++) {
        float xcur[CC];
#pragma unroll
        for (int c = 0; c < CC; c++)
            xcur[c] = xb[(size_t)(t * CC + c) * NPIX];

        // ---- layer 0 ----
        {
            float4 z[16];
            const float* bb = P + OFF_B0 + hw4;
#pragma unroll
            for (int j = 0; j < 16; j++)
                z[j] = *(const float4*)(bb + 4 * j);
#pragma unroll 1
            for (int c = 0; c < CC; c++)
                ROW_ACC(P + OFF_L0I + c * 128 + hw4, xcur[c]);
#pragma unroll 1
            for (int k = 0; k < HH; k++) {
                float hv = H0[k * 128 + pxl];     // h0(t-1)
                ROW_ACC(P + OFF_L0H + k * 128 + hw4, hv);
            }
            __syncthreads();                      // all waves done reading old H0
#pragma unroll
            for (int j = 0; j < 16; j++) {
                float cn = sigf(z[j].y) * c0[j] + sigf(z[j].x) * tanhf_(z[j].z);
                c0[j] = cn;
                H0[(hw + j) * 128 + pxl] = sigf(z[j].w) * tanhf_(cn);
            }
            __syncthreads();                      // new H0 visible
        }

        // ---- layer 1 ----
        {
            float4 z[16];
            const float* bb = P + OFF_B1 + hw4;
#pragma unroll
            for (int j = 0; j < 16; j++)
                z[j] = *(const float4*)(bb + 4 * j);
#pragma unroll 1
            for (int k = 0; k < HH; k++) {
                float hv = H0[k * 128 + pxl];     // h0(t)
                ROW_ACC(P + OFF_L1I + k * 128 + hw4, hv);
            }
#pragma unroll 1
            for (int k = 0; k < HH; k++) {
                float hv = H1[k * 128 + pxl];     // h1(t-1)
                ROW_ACC(P + OFF_L1H + k * 128 + hw4, hv);
            }
            __syncthreads();                      // all waves done reading old H1
#pragma unroll
            for (int j = 0; j < 16; j++) {
                float cn = sigf(z[j].y) * c1[j] + sigf(z[j].x) * tanhf_(z[j].z);
                c1[j] = cn;
                H1[(hw + j) * 128 + pxl] = sigf(z[j].w) * tanhf_(cn);
            }
            __syncthreads();                      // new H1 visible
        }
    }

    // ---- fc1 + relu: half picks 32 of the 64 output channels ----
    float f[32];
    {
        const float* fb1 = P + OFF_FC1B + (half << 5);
#pragma unroll
        for (int m = 0; m < 32; m++) f[m] = fb1[m];
    }
#pragma unroll 1
    for (int k = 0; k < HH; k++) {
        float hv = H1[k * 128 + pxl];
        const float* wr = P + OFF_FC1W + k * 64 + (half << 5);
#pragma unroll
        for (int m = 0; m < 32; m++)
            f[m] = __builtin_fmaf(wr[m], hv, f[m]);
    }
    float* fob = feats + (size_t)b * WIDTH * NPIX + (size_t)(half * 32) * NPIX + pix;
#pragma unroll
    for (int m = 0; m < 32; m++)
        fob[(size_t)m * NPIX] = fmaxf(f[m], 0.f);
}

// ---------------- fused conv layer (unchanged: 256 thr, 1 px/lane) ----------------
__global__ __launch_bounds__(256, 1)
void conv_fused_kernel(const float* __restrict__ Fin, float* __restrict__ Fout,
                       const float* __restrict__ P, int k) {
    __shared__ float4 CW[1024];   // [co2][ci2]
    __shared__ float  CB[64];
    {
        const float4* src = (const float4*)(P + OFF_CWT2 + k * 4096);
        for (int i = threadIdx.x; i < 1024; i += 256) CW[i] = src[i];
        if (threadIdx.x < 64) CB[threadIdx.x] = P[OFF_CB + k * 64 + threadIdx.x];
    }
    __syncthreads();

    int n = blockIdx.x * 256 + threadIdx.x;
    int b = n >> 16;
    int pix = n & (NPIX - 1);
    int i = pix >> 8, j = pix & 255;
    float wstr = P[OFF_GW + 2 * k], wdiag = P[OFF_GW + 2 * k + 1];
    float fu = (i > 0) ? wstr : 0.f, fd = (i < 255) ? wstr : 0.f;
    float fl = (j > 0) ? wstr : 0.f, fr = (j < 255) ? wstr : 0.f;
    float ful = (i > 0 && j > 0) ? wdiag : 0.f, fur = (i > 0 && j < 255) ? wdiag : 0.f;
    float fdl = (i < 255 && j > 0) ? wdiag : 0.f, fdr = (i < 255 && j < 255) ? wdiag : 0.f;

    const float* fb = Fin + (size_t)b * WIDTH * NPIX + pix;
    float u[WIDTH];
#pragma unroll
    for (int ch = 0; ch < WIDTH; ch++) {
        const float* yc = fb + (size_t)ch * NPIX;
        float v = yc[0];
        v += fu * yc[-256] + fd * yc[256] + fl * yc[-1] + fr * yc[1];
        v += ful * yc[-257] + fur * yc[-255] + fdl * yc[255] + fdr * yc[257];
        u[ch] = v;
    }

    float* ob = Fout + (size_t)b * WIDTH * NPIX + pix;
#pragma unroll 1
    for (int co2 = 0; co2 < 32; co2++) {
        float ax = CB[2 * co2], ay = CB[2 * co2 + 1];
        const float4* wv = CW + co2 * 32;
#pragma unroll
        for (int ci2 = 0; ci2 < 32; ci2++) {
            float4 q = wv[ci2];
            float a0 = u[2 * ci2], a1 = u[2 * ci2 + 1];
            ax = __builtin_fmaf(q.x, a0, ax); ax = __builtin_fmaf(q.z, a1, ax);
            ay = __builtin_fmaf(q.y, a0, ay); ay = __builtin_fmaf(q.w, a1, ay);
        }
        ob[(size_t)(2 * co2) * NPIX]     = fmaxf(ax, 0.f);
        ob[(size_t)(2 * co2 + 1) * NPIX] = fmaxf(ay, 0.f);
    }
}

// ---------------- last conv (no relu) + fc2/fc3 head (unchanged) ----------------
__global__ __launch_bounds__(256, 1)
void conv_head_kernel(const float* __restrict__ Fin, const float* __restrict__ P,
                      float* __restrict__ out) {
    const int k = 3;
    __shared__ float4 CW3[1024];
    __shared__ float  CB3[64];
    __shared__ float4 F2W[512];
    __shared__ float  F2B[32];
    __shared__ float4 F3W[80];
    __shared__ float  F3B[12];
    {
        const float4* s1 = (const float4*)(P + OFF_CWT2 + k * 4096);
        for (int i = threadIdx.x; i < 1024; i += 256) CW3[i] = s1[i];
        const float4* s2 = (const float4*)(P + OFF_FC2W2);
        for (int i = threadIdx.x; i < 512; i += 256) F2W[i] = s2[i];
        const float4* s3 = (const float4*)(P + OFF_FC3W4);
        if (threadIdx.x < 80) F3W[threadIdx.x] = s3[threadIdx.x];
        if (threadIdx.x < 64) CB3[threadIdx.x] = P[OFF_CB + k * 64 + threadIdx.x];
        if (threadIdx.x < 32) F2B[threadIdx.x] = P[OFF_FC2B + threadIdx.x];
        if (threadIdx.x < 10) F3B[threadIdx.x] = P[OFF_FC3B + threadIdx.x];
    }
    __syncthreads();

    int n = blockIdx.x * 256 + threadIdx.x;
    int b = n >> 16;
    int pix = n & (NPIX - 1);
    int i = pix >> 8, j = pix & 255;
    float wstr = P[OFF_GW + 2 * k], wdiag = P[OFF_GW + 2 * k + 1];
    float fu = (i > 0) ? wstr : 0.f, fd = (i < 255) ? wstr : 0.f;
    float fl = (j > 0) ? wstr : 0.f, fr = (j < 255) ? wstr : 0.f;
    float ful = (i > 0 && j > 0) ? wdiag : 0.f, fur = (i > 0 && j < 255) ? wdiag : 0.f;
    float fdl = (i < 255 && j > 0) ? wdiag : 0.f, fdr = (i < 255 && j < 255) ? wdiag : 0.f;

    const float* fb = Fin + (size_t)b * WIDTH * NPIX + pix;
    float u[WIDTH];
#pragma unroll
    for (int ch = 0; ch < WIDTH; ch++) {
        const float* yc = fb + (size_t)ch * NPIX;
        float v = yc[0];
        v += fu * yc[-256] + fd * yc[256] + fl * yc[-1] + fr * yc[1];
        v += ful * yc[-257] + fur * yc[-255] + fdl * yc[255] + fdr * yc[257];
        u[ch] = v;
    }

    float f[WIDTH];
#pragma unroll
    for (int co2 = 0; co2 < 32; co2++) {
        float ax = CB3[2 * co2], ay = CB3[2 * co2 + 1];
        const float4* wv = CW3 + co2 * 32;
#pragma unroll
        for (int ci2 = 0; ci2 < 32; ci2++) {
            float4 q = wv[ci2];
            float a0 = u[2 * ci2], a1 = u[2 * ci2 + 1];
            ax = __builtin_fmaf(q.x, a0, ax); ax = __builtin_fmaf(q.z, a1, ax);
            ay = __builtin_fmaf(q.y, a0, ay); ay = __builtin_fmaf(q.w, a1, ay);
        }
        f[2 * co2] = ax; f[2 * co2 + 1] = ay;
    }

    float2 oo[5];
#pragma unroll
    for (int oc2 = 0; oc2 < 5; oc2++) oo[oc2] = make_float2(F3B[2 * oc2], F3B[2 * oc2 + 1]);
#pragma unroll 1
    for (int m2 = 0; m2 < 16; m2++) {
        float ax = F2B[2 * m2], ay = F2B[2 * m2 + 1];
        const float4* wv = F2W + m2 * 32;
#pragma unroll
        for (int ch2 = 0; ch2 < 32; ch2++) {
            float4 q = wv[ch2];
            ax = __builtin_fmaf(q.x, f[2 * ch2], ax); ax = __builtin_fmaf(q.z, f[2 * ch2 + 1], ax);
            ay = __builtin_fmaf(q.y, f[2 * ch2], ay); ay = __builtin_fmaf(q.w, f[2 * ch2 + 1], ay);
        }
        ax = fmaxf(ax, 0.f); ay = fmaxf(ay, 0.f);
#pragma unroll
        for (int oc2 = 0; oc2 < 5; oc2++) {
            float4 q = F3W[oc2 * 16 + m2];
            oo[oc2].x += q.x * ax + q.z * ay;
            oo[oc2].y += q.y * ax + q.w * ay;
        }
    }
    float* ob = out + (size_t)b * OUTC * NPIX + pix;
#pragma unroll
    for (int oc2 = 0; oc2 < 5; oc2++) {
        ob[(size_t)(2 * oc2) * NPIX]     = oo[oc2].x;
        ob[(size_t)(2 * oc2 + 1) * NPIX] = oo[oc2].y;
    }
}

extern "C" void kernel_launch(void* const* d_in, const int* in_sizes, int n_in,
                              void* d_out, int out_size, void* d_ws, size_t ws_size,
                              hipStream_t stream) {
    const float* x     = (const float*)d_in[0];
    const float* eattr = (const float*)d_in[3];
    const float* Wih0  = (const float*)d_in[4];
    const float* Whh0  = (const float*)d_in[5];
    const float* bih0  = (const float*)d_in[6];
    const float* bhh0  = (const float*)d_in[7];
    const float* Wih1  = (const float*)d_in[8];
    const float* Whh1  = (const float*)d_in[9];
    const float* bih1  = (const float*)d_in[10];
    const float* bhh1  = (const float*)d_in[11];
    const float* fc1w  = (const float*)d_in[12];
    const float* fc1b  = (const float*)d_in[13];
    const float* convw = (const float*)d_in[14];
    const float* convb = (const float*)d_in[15];
    const float* gparam= (const float*)d_in[16];
    const float* fc2w  = (const float*)d_in[17];
    const float* fc2b  = (const float*)d_in[18];
    const float* fc3w  = (const float*)d_in[19];
    const float* fc3b  = (const float*)d_in[20];

    float* P  = (float*)d_ws;
    float* FA = P + OFF_FEATS_A;
    float* FB = P + OFF_FEATS_B;

    prep_kernel<<<64, 256, 0, stream>>>(Wih0, Whh0, bih0, bhh0, Wih1, Whh1, bih1, bhh1,
                                        fc1w, fc1b, convw, convb, fc2w, fc2b, fc3w, fc3b,
                                        gparam, eattr, P);
    lstm_fc1_kernel<<<1024, 256, 0, stream>>>(x, P, FA);
    conv_fused_kernel<<<512, 256, 0, stream>>>(FA, FB, P, 0);
    conv_fused_kernel<<<512, 256, 0, stream>>>(FB, FA, P, 1);
    conv_fused_kernel<<<512, 256, 0, stream>>>(FA, FB, P, 2);
    conv_head_kernel<<<512, 256, 0, stream>>>(FB, P, (float*)d_out);
}

// Round 5
// 600.416 us; speedup vs baseline: 4.8706x; 1.0900x over previous
//
#include <hip/hip_runtime.h>
#include <hip/hip_bf16.h>

#define NPIX   65536
#define TT     5
#define CC     10
#define HH     32
#define WIDTH  64
#define KW     32
#define OUTC   10

// ---- workspace layout (float offsets) ----
// LSTM weights k-major gate-packed for SGPR streaming: [k][j][g], g=(i,f,g,o)
#define OFF_L0I    0        // 1280  [c][j][g]
#define OFF_L0H    1280     // 4096  [k][j][g]
#define OFF_L1I    5376     // 4096
#define OFF_L1H    9472     // 4096
#define OFF_B0     13568    // 128   [j][g]
#define OFF_B1     13696    // 128
#define OFF_FC1W   13824    // 2048  [k][ch]
#define OFF_FC1B   15872    // 64
#define OFF_CWT2   16384    // 16384 [k][co2][ci] float2 (conv, LDS-staged)
#define OFF_CB     32768    // 256
#define OFF_FC2W2  33024    // 2048  [m2][ch] float2
#define OFF_FC2B   35072    // 32
#define OFF_FC3W4  35104    // 320   [oc2][m2] float4
#define OFF_FC3B   35424    // 16
#define OFF_GW     35440    // 8
#define OFF_FEATS_A 36864
#define OFF_FEATS_B (36864 + 8388608)

#define STRAIGHT_ATTR_IDX (65025 * 3)

typedef float v2f __attribute__((ext_vector_type(2)));

__device__ __forceinline__ float sigf(float x)  { return 1.0f / (1.0f + __expf(-x)); }
__device__ __forceinline__ float tanhf_(float x){ return 1.0f - 2.0f / (__expf(2.0f * x) + 1.0f); }

// ---------------- prep: pack params ----------------
__global__ __launch_bounds__(256, 1)
void prep_kernel(const float* Wih0, const float* Whh0,
                 const float* bih0, const float* bhh0,
                 const float* Wih1, const float* Whh1,
                 const float* bih1, const float* bhh1,
                 const float* fc1w, const float* fc1b,
                 const float* convw, const float* convb,
                 const float* fc2w, const float* fc2b,
                 const float* fc3w, const float* fc3b,
                 const float* gparam, const float* eattr,
                 float* P) {
    int tid = blockIdx.x * blockDim.x + threadIdx.x;
    int stride = gridDim.x * blockDim.x;
    // LSTM k-major: [k][j][g] <- W[(g*32+j)*K + k]
    for (int idx = tid; idx < 1280; idx += stride) {
        int g = idx & 3, j = (idx >> 2) & 31, c = idx >> 7;
        P[OFF_L0I + idx] = Wih0[(g * 32 + j) * 10 + c];
    }
    for (int idx = tid; idx < 4096; idx += stride) {
        int g = idx & 3, j = (idx >> 2) & 31, k = idx >> 7;
        P[OFF_L0H + idx] = Whh0[(g * 32 + j) * 32 + k];
        P[OFF_L1I + idx] = Wih1[(g * 32 + j) * 32 + k];
        P[OFF_L1H + idx] = Whh1[(g * 32 + j) * 32 + k];
    }
    for (int idx = tid; idx < 128; idx += stride) {
        int g = idx & 3, j = idx >> 2;
        P[OFF_B0 + idx] = bih0[g * 32 + j] + bhh0[g * 32 + j];
        P[OFF_B1 + idx] = bih1[g * 32 + j] + bhh1[g * 32 + j];
    }
    // fc1 k-major [k][ch]
    for (int idx = tid; idx < 2048; idx += stride) {
        int ch = idx & 63, k = idx >> 6;
        P[OFF_FC1W + idx] = fc1w[ch * 32 + k];
    }
    for (int i = tid; i < 64; i += stride) P[OFF_FC1B + i] = fc1b[i];
    // conv [k][co2][ci] float2
    for (int idx = tid; idx < 16384; idx += stride) {
        int k = idx >> 12, r = idx & 4095, e = r >> 1, h = r & 1;
        int co2 = e >> 6, ci = e & 63;
        P[OFF_CWT2 + idx] = convw[k * 4096 + ci * 64 + (2 * co2 + h)];
    }
    for (int i = tid; i < 256; i += stride) P[OFF_CB + i] = convb[i];
    for (int idx = tid; idx < 2048; idx += stride) {
        int e = idx >> 1, h = idx & 1, m2 = e >> 6, ch = e & 63;
        P[OFF_FC2W2 + idx] = fc2w[(2 * m2 + h) * 64 + ch];
    }
    for (int i = tid; i < 32;  i += stride) P[OFF_FC2B + i] = fc2b[i];
    for (int idx = tid; idx < 320; idx += stride) {
        int q = idx & 3, e = idx >> 2, oc2 = e >> 4, m2 = e & 15;
        int oc = 2 * oc2 + (q & 1), m = 2 * m2 + (q >> 1);
        P[OFF_FC3W4 + idx] = fc3w[oc * 32 + m];
    }
    for (int i = tid; i < 10; i += stride) P[OFF_FC3B + i] = fc3b[i];
    for (int idx = tid; idx < 8; idx += stride) {
        int k = idx >> 1;
        float g = gparam[k];
        float denom = g * g + 1e-8f;
        float a = (idx & 1) ? eattr[0] : eattr[STRAIGHT_ATTR_IDX];
        P[OFF_GW + idx] = __expf(-(a * a) / denom);
    }
}

// ---------------- LSTM: wave-level j-split + packed fp32 FMA ----------------
// 128 thr/block = 2 waves, 64 px/block. Wave 0 owns hidden units j in [0,16),
// wave 1 owns [16,32). half = readfirstlane(tid>>6) is SGPR -> weight
// addresses wave-uniform -> s_load. Accumulators as v2f pairs ->
// v_pk_fma_f32 (2 IEEE fp32 FMA / issue slot, bit-identical): R3 measured
// ~2 issue-slots per scalar FMA; packing halves slot count at zero extra
// register bytes (z still 64 floats = 32 pairs). launch_bounds 2nd arg MUST
// stay 1 (arg 4 imposed a 64-VGPR cap -> spill disaster, R1/R2).
// LDS 16KB/block -> ~8 blocks/CU co-residency to de-lockstep barrier phases.
#define ROW_ACC(WBASE, SVAL) do {                                        \
    const v2f* wr_ = (const v2f*)(WBASE);                                \
    float s_ = (SVAL); v2f sv_ = {s_, s_};                               \
    _Pragma("unroll")                                                    \
    for (int j_ = 0; j_ < 16; j_++) {                                    \
        zA[j_] = __builtin_elementwise_fma(wr_[2 * j_],     sv_, zA[j_]);\
        zB[j_] = __builtin_elementwise_fma(wr_[2 * j_ + 1], sv_, zB[j_]);\
    } } while (0)

__global__ __launch_bounds__(128, 1)
void lstm_fc1_kernel(const float* __restrict__ x,
                     const float* __restrict__ P,
                     float* __restrict__ feats) {
    __shared__ float H0[HH * 64];    // 8192 B  [j][pxl]
    __shared__ float H1[HH * 64];    // 8192 B  (total 16384)

    int tid  = threadIdx.x;
    int half = __builtin_amdgcn_readfirstlane(tid >> 6);  // wave id: 0 or 1
    int pxl  = tid & 63;             // pixel column within block
    int hw   = half << 4;            // j offset: 0 or 16
    int hw4  = half << 6;            // float offset into 128-wide gate rows

    int n = blockIdx.x * 64 + pxl;
    int b = n >> 16;
    int pix = n & (NPIX - 1);
    const float* xb = x + (size_t)b * TT * CC * NPIX + pix;

    float c0[16], c1[16];
#pragma unroll
    for (int j = 0; j < 16; j++) {
        c0[j] = 0.f; c1[j] = 0.f;
        H0[(hw + j) * 64 + pxl] = 0.f;
        H1[(hw + j) * 64 + pxl] = 0.f;
    }
    __syncthreads();

#pragma unroll 1
    for (int t = 0; t < TT; t++) {
        float xcur[CC];
#pragma unroll
        for (int c = 0; c < CC; c++)
            xcur[c] = xb[(size_t)(t * CC + c) * NPIX];

        // ---- layer 0 ----
        {
            v2f zA[16], zB[16];      // zA=(i,f), zB=(g,o) per owned unit
            const v2f* bb = (const v2f*)(P + OFF_B0 + hw4);
#pragma unroll
            for (int j = 0; j < 16; j++) {
                zA[j] = bb[2 * j];
                zB[j] = bb[2 * j + 1];
            }
#pragma unroll 1
            for (int c = 0; c < CC; c++)
                ROW_ACC(P + OFF_L0I + c * 128 + hw4, xcur[c]);
#pragma unroll 1
            for (int k = 0; k < HH; k++) {
                float hv = H0[k * 64 + pxl];      // h0(t-1)
                ROW_ACC(P + OFF_L0H + k * 128 + hw4, hv);
            }
            __syncthreads();                      // all waves done reading old H0
#pragma unroll
            for (int j = 0; j < 16; j++) {
                float cn = sigf(zA[j].y) * c0[j] + sigf(zA[j].x) * tanhf_(zB[j].x);
                c0[j] = cn;
                H0[(hw + j) * 64 + pxl] = sigf(zB[j].y) * tanhf_(cn);
            }
            __syncthreads();                      // new H0 visible
        }

        // ---- layer 1 ----
        {
            v2f zA[16], zB[16];
            const v2f* bb = (const v2f*)(P + OFF_B1 + hw4);
#pragma unroll
            for (int j = 0; j < 16; j++) {
                zA[j] = bb[2 * j];
                zB[j] = bb[2 * j + 1];
            }
#pragma unroll 1
            for (int k = 0; k < HH; k++) {
                float hv = H0[k * 64 + pxl];      // h0(t)
                ROW_ACC(P + OFF_L1I + k * 128 + hw4, hv);
            }
#pragma unroll 1
            for (int k = 0; k < HH; k++) {
                float hv = H1[k * 64 + pxl];      // h1(t-1)
                ROW_ACC(P + OFF_L1H + k * 128 + hw4, hv);
            }
            __syncthreads();                      // all waves done reading old H1
#pragma unroll
            for (int j = 0; j < 16; j++) {
                float cn = sigf(zA[j].y) * c1[j] + sigf(zA[j].x) * tanhf_(zB[j].x);
                c1[j] = cn;
                H1[(hw + j) * 64 + pxl] = sigf(zB[j].y) * tanhf_(cn);
            }
            __syncthreads();                      // new H1 visible
        }
    }

    // ---- fc1 + relu: half picks 32 of the 64 output channels, packed ----
    v2f fv[16];
    {
        const v2f* fb1 = (const v2f*)(P + OFF_FC1B + (half << 5));
#pragma unroll
        for (int m = 0; m < 16; m++) fv[m] = fb1[m];
    }
#pragma unroll 1
    for (int k = 0; k < HH; k++) {
        float hv = H1[k * 64 + pxl];
        v2f h2 = {hv, hv};
        const v2f* wr = (const v2f*)(P + OFF_FC1W + k * 64 + (half << 5));
#pragma unroll
        for (int m = 0; m < 16; m++)
            fv[m] = __builtin_elementwise_fma(wr[m], h2, fv[m]);
    }
    float* fob = feats + (size_t)b * WIDTH * NPIX + (size_t)(half * 32) * NPIX + pix;
#pragma unroll
    for (int m = 0; m < 16; m++) {
        fob[(size_t)(2 * m) * NPIX]     = fmaxf(fv[m].x, 0.f);
        fob[(size_t)(2 * m + 1) * NPIX] = fmaxf(fv[m].y, 0.f);
    }
}

// ---------------- fused conv layer (unchanged: 256 thr, 1 px/lane) ----------------
__global__ __launch_bounds__(256, 1)
void conv_fused_kernel(const float* __restrict__ Fin, float* __restrict__ Fout,
                       const float* __restrict__ P, int k) {
    __shared__ float4 CW[1024];   // [co2][ci2]
    __shared__ float  CB[64];
    {
        const float4* src = (const float4*)(P + OFF_CWT2 + k * 4096);
        for (int i = threadIdx.x; i < 1024; i += 256) CW[i] = src[i];
        if (threadIdx.x < 64) CB[threadIdx.x] = P[OFF_CB + k * 64 + threadIdx.x];
    }
    __syncthreads();

    int n = blockIdx.x * 256 + threadIdx.x;
    int b = n >> 16;
    int pix = n & (NPIX - 1);
    int i = pix >> 8, j = pix & 255;
    float wstr = P[OFF_GW + 2 * k], wdiag = P[OFF_GW + 2 * k + 1];
    float fu = (i > 0) ? wstr : 0.f, fd = (i < 255) ? wstr : 0.f;
    float fl = (j > 0) ? wstr : 0.f, fr = (j < 255) ? wstr : 0.f;
    float ful = (i > 0 && j > 0) ? wdiag : 0.f, fur = (i > 0 && j < 255) ? wdiag : 0.f;
    float fdl = (i < 255 && j > 0) ? wdiag : 0.f, fdr = (i < 255 && j < 255) ? wdiag : 0.f;

    const float* fb = Fin + (size_t)b * WIDTH * NPIX + pix;
    float u[WIDTH];
#pragma unroll
    for (int ch = 0; ch < WIDTH; ch++) {
        const float* yc = fb + (size_t)ch * NPIX;
        float v = yc[0];
        v += fu * yc[-256] + fd * yc[256] + fl * yc[-1] + fr * yc[1];
        v += ful * yc[-257] + fur * yc[-255] + fdl * yc[255] + fdr * yc[257];
        u[ch] = v;
    }

    float* ob = Fout + (size_t)b * WIDTH * NPIX + pix;
#pragma unroll 1
    for (int co2 = 0; co2 < 32; co2++) {
        float ax = CB[2 * co2], ay = CB[2 * co2 + 1];
        const float4* wv = CW + co2 * 32;
#pragma unroll
        for (int ci2 = 0; ci2 < 32; ci2++) {
            float4 q = wv[ci2];
            float a0 = u[2 * ci2], a1 = u[2 * ci2 + 1];
            ax = __builtin_fmaf(q.x, a0, ax); ax = __builtin_fmaf(q.z, a1, ax);
            ay = __builtin_fmaf(q.y, a0, ay); ay = __builtin_fmaf(q.w, a1, ay);
        }
        ob[(size_t)(2 * co2) * NPIX]     = fmaxf(ax, 0.f);
        ob[(size_t)(2 * co2 + 1) * NPIX] = fmaxf(ay, 0.f);
    }
}

// ---------------- last conv (no relu) + fc2/fc3 head (unchanged) ----------------
__global__ __launch_bounds__(256, 1)
void conv_head_kernel(const float* __restrict__ Fin, const float* __restrict__ P,
                      float* __restrict__ out) {
    const int k = 3;
    __shared__ float4 CW3[1024];
    __shared__ float  CB3[64];
    __shared__ float4 F2W[512];
    __shared__ float  F2B[32];
    __shared__ float4 F3W[80];
    __shared__ float  F3B[12];
    {
        const float4* s1 = (const float4*)(P + OFF_CWT2 + k * 4096);
        for (int i = threadIdx.x; i < 1024; i += 256) CW3[i] = s1[i];
        const float4* s2 = (const float4*)(P + OFF_FC2W2);
        for (int i = threadIdx.x; i < 512; i += 256) F2W[i] = s2[i];
        const float4* s3 = (const float4*)(P + OFF_FC3W4);
        if (threadIdx.x < 80) F3W[threadIdx.x] = s3[threadIdx.x];
        if (threadIdx.x < 64) CB3[threadIdx.x] = P[OFF_CB + k * 64 + threadIdx.x];
        if (threadIdx.x < 32) F2B[threadIdx.x] = P[OFF_FC2B + threadIdx.x];
        if (threadIdx.x < 10) F3B[threadIdx.x] = P[OFF_FC3B + threadIdx.x];
    }
    __syncthreads();

    int n = blockIdx.x * 256 + threadIdx.x;
    int b = n >> 16;
    int pix = n & (NPIX - 1);
    int i = pix >> 8, j = pix & 255;
    float wstr = P[OFF_GW + 2 * k], wdiag = P[OFF_GW + 2 * k + 1];
    float fu = (i > 0) ? wstr : 0.f, fd = (i < 255) ? wstr : 0.f;
    float fl = (j > 0) ? wstr : 0.f, fr = (j < 255) ? wstr : 0.f;
    float ful = (i > 0 && j > 0) ? wdiag : 0.f, fur = (i > 0 && j < 255) ? wdiag : 0.f;
    float fdl = (i < 255 && j > 0) ? wdiag : 0.f, fdr = (i < 255 && j < 255) ? wdiag : 0.f;

    const float* fb = Fin + (size_t)b * WIDTH * NPIX + pix;
    float u[WIDTH];
#pragma unroll
    for (int ch = 0; ch < WIDTH; ch++) {
        const float* yc = fb + (size_t)ch * NPIX;
        float v = yc[0];
        v += fu * yc[-256] + fd * yc[256] + fl * yc[-1] + fr * yc[1];
        v += ful * yc[-257] + fur * yc[-255] + fdl * yc[255] + fdr * yc[257];
        u[ch] = v;
    }

    float f[WIDTH];
#pragma unroll
    for (int co2 = 0; co2 < 32; co2++) {
        float ax = CB3[2 * co2], ay = CB3[2 * co2 + 1];
        const float4* wv = CW3 + co2 * 32;
#pragma unroll
        for (int ci2 = 0; ci2 < 32; ci2++) {
            float4 q = wv[ci2];
            float a0 = u[2 * ci2], a1 = u[2 * ci2 + 1];
            ax = __builtin_fmaf(q.x, a0, ax); ax = __builtin_fmaf(q.z, a1, ax);
            ay = __builtin_fmaf(q.y, a0, ay); ay = __builtin_fmaf(q.w, a1, ay);
        }
        f[2 * co2] = ax; f[2 * co2 + 1] = ay;
    }

    float2 oo[5];
#pragma unroll
    for (int oc2 = 0; oc2 < 5; oc2++) oo[oc2] = make_float2(F3B[2 * oc2], F3B[2 * oc2 + 1]);
#pragma unroll 1
    for (int m2 = 0; m2 < 16; m2++) {
        float ax = F2B[2 * m2], ay = F2B[2 * m2 + 1];
        const float4* wv = F2W + m2 * 32;
#pragma unroll
        for (int ch2 = 0; ch2 < 32; ch2++) {
            float4 q = wv[ch2];
            ax = __builtin_fmaf(q.x, f[2 * ch2], ax); ax = __builtin_fmaf(q.z, f[2 * ch2 + 1], ax);
            ay = __builtin_fmaf(q.y, f[2 * ch2], ay); ay = __builtin_fmaf(q.w, f[2 * ch2 + 1], ay);
        }
        ax = fmaxf(ax, 0.f); ay = fmaxf(ay, 0.f);
#pragma unroll
        for (int oc2 = 0; oc2 < 5; oc2++) {
            float4 q = F3W[oc2 * 16 + m2];
            oo[oc2].x += q.x * ax + q.z * ay;
            oo[oc2].y += q.y * ax + q.w * ay;
        }
    }
    float* ob = out + (size_t)b * OUTC * NPIX + pix;
#pragma unroll
    for (int oc2 = 0; oc2 < 5; oc2++) {
        ob[(size_t)(2 * oc2) * NPIX]     = oo[oc2].x;
        ob[(size_t)(2 * oc2 + 1) * NPIX] = oo[oc2].y;
    }
}

extern "C" void kernel_launch(void* const* d_in, const int* in_sizes, int n_in,
                              void* d_out, int out_size, void* d_ws, size_t ws_size,
                              hipStream_t stream) {
    const float* x     = (const float*)d_in[0];
    const float* eattr = (const float*)d_in[3];
    const float* Wih0  = (const float*)d_in[4];
    const float* Whh0  = (const float*)d_in[5];
    const float* bih0  = (const float*)d_in[6];
    const float* bhh0  = (const float*)d_in[7];
    const float* Wih1  = (const float*)d_in[8];
    const float* Whh1  = (const float*)d_in[9];
    const float* bih1  = (const float*)d_in[10];
    const float* bhh1  = (const float*)d_in[11];
    const float* fc1w  = (const float*)d_in[12];
    const float* fc1b  = (const float*)d_in[13];
    const float* convw = (const float*)d_in[14];
    const float* convb = (const float*)d_in[15];
    const float* gparam= (const float*)d_in[16];
    const float* fc2w  = (const float*)d_in[17];
    const float* fc2b  = (const float*)d_in[18];
    const float* fc3w  = (const float*)d_in[19];
    const float* fc3b  = (const float*)d_in[20];

    float* P  = (float*)d_ws;
    float* FA = P + OFF_FEATS_A;
    float* FB = P + OFF_FEATS_B;

    prep_kernel<<<64, 256, 0, stream>>>(Wih0, Whh0, bih0, bhh0, Wih1, Whh1, bih1, bhh1,
                                        fc1w, fc1b, convw, convb, fc2w, fc2b, fc3w, fc3b,
                                        gparam, eattr, P);
    lstm_fc1_kernel<<<2048, 128, 0, stream>>>(x, P, FA);
    conv_fused_kernel<<<512, 256, 0, stream>>>(FA, FB, P, 0);
    conv_fused_kernel<<<512, 256, 0, stream>>>(FB, FA, P, 1);
    conv_fused_kernel<<<512, 256, 0, stream>>>(FA, FB, P, 2);
    conv_head_kernel<<<512, 256, 0, stream>>>(FB, P, (float*)d_out);
}